// Round 18
// baseline (535.790 us; speedup 1.0000x reference)
//
#include <hip/hip_runtime.h>
#include <cstdint>

#define CC 1000
#define KK 2
#define DD 128

typedef short bf16x8 __attribute__((ext_vector_type(8)));
typedef float f32x16 __attribute__((ext_vector_type(16)));
typedef int   i32x4  __attribute__((ext_vector_type(4)));
typedef unsigned int u32x2 __attribute__((ext_vector_type(2)));

// HW packed f32->bf16 (RTNE); 1 instr vs ~9 for the software pack.
__device__ __forceinline__ uint32_t cvtpk(float lo, float hi) {
    uint32_t r;
    asm("v_cvt_pk_bf16_f32 %0, %1, %2" : "=v"(r) : "v"(lo), "v"(hi));
    return r;
}
__device__ __forceinline__ f32x16 zero16() {
    f32x16 v;
    #pragma unroll
    for (int p = 0; p < 16; ++p) v[p] = 0.f;
    return v;
}

struct Frag8 { uint32_t a0, a1, a2, a3, b0, b1, b2, b3; };

__device__ __forceinline__ bf16x8 flo(const Frag8 f) {
    i32x4 t; t[0] = (int)f.a0; t[1] = (int)f.a1; t[2] = (int)f.a2; t[3] = (int)f.a3;
    return __builtin_bit_cast(bf16x8, t);
}
__device__ __forceinline__ bf16x8 fhi(const Frag8 f) {
    i32x4 t; t[0] = (int)f.b0; t[1] = (int)f.b1; t[2] = (int)f.b2; t[3] = (int)f.b3;
    return __builtin_bit_cast(bf16x8, t);
}

// C-layout fp32 tile -> B-fragment words (verified rounds 4..17).
// permlane32_swap(W2, W0): returns {out2=[W0.hi||W2.hi], out0=[W0.lo||W2.lo]}.
__device__ __forceinline__ Frag8 build_frags(const f32x16 t) {
    uint32_t W0 = cvtpk(t[0],  t[1]),  W1 = cvtpk(t[2],  t[3]);
    uint32_t W2 = cvtpk(t[4],  t[5]),  W3 = cvtpk(t[6],  t[7]);
    uint32_t W4 = cvtpk(t[8],  t[9]),  W5 = cvtpk(t[10], t[11]);
    uint32_t W6 = cvtpk(t[12], t[13]), W7 = cvtpk(t[14], t[15]);
    u32x2 p02 = __builtin_amdgcn_permlane32_swap(W2, W0, false, false);
    u32x2 p13 = __builtin_amdgcn_permlane32_swap(W3, W1, false, false);
    u32x2 p46 = __builtin_amdgcn_permlane32_swap(W6, W4, false, false);
    u32x2 p57 = __builtin_amdgcn_permlane32_swap(W7, W5, false, false);
    Frag8 f;
    f.a0 = p02[1]; f.a1 = p13[1]; f.a2 = p02[0]; f.a3 = p13[0];
    f.b0 = p46[1]; f.b1 = p57[1]; f.b2 = p46[0]; f.b3 = p57[0];
    return f;
}

__device__ __forceinline__ f32x16 off_apply(const char* Ep, const Frag8 yj, f32x16 acc) {
    bf16x8 A0 = *(const bf16x8*)(Ep);
    bf16x8 A1 = *(const bf16x8*)(Ep + 32);
    acc = __builtin_amdgcn_mfma_f32_32x32x16_bf16(A0, flo(yj), acc, 0, 0, 0);
    acc = __builtin_amdgcn_mfma_f32_32x32x16_bf16(A1, fhi(yj), acc, 0, 0, 0);
    return acc;
}
__device__ __forceinline__ f32x16 m_solve(const char* Mp, const Frag8 tf) {
    bf16x8 MA0 = *(const bf16x8*)(Mp);
    bf16x8 MA1 = *(const bf16x8*)(Mp + 32);
    f32x16 y = zero16();
    y = __builtin_amdgcn_mfma_f32_32x32x16_bf16(MA0, flo(tf), y, 0, 0, 0);
    y = __builtin_amdgcn_mfma_f32_32x32x16_bf16(MA1, fhi(tf), y, 0, 0, 0);
    return y;
}

// LDS layout (rows stride 80B):
//   [0,10240)      Sm:  4 diag blocks, first -S_i, overwritten by M'_i
//   [10240,20480)  Tt:  (I-S_i)^T (B-layout) -- DEAD after M' compute
//   [10240,25600)  Eoff: 6 off-diag -L_ij blocks, staged AFTER M' (overwrites Tt)
//   [25600,27648)  PAD: pins total LDS so implied occupancy = 5 blocks/CU ->
//                  RA budget 512/5 = 102 VGPR (round 17: verified win).
//
// ROUND-18: combine kernel FOLDED IN via last-block-wins. Each (c,k) block
// writes its lp row to ws, __threadfence (device scope, G16), atomicAdd on
// cnt[c] (memset to 0 each call); the block seeing old==1 reads the partner
// row and writes out for all 256 columns. Output is k-indexed -> identical
// regardless of which block wins (deterministic).
__global__ __launch_bounds__(256, 1) void mda_partial_kernel(
    const float* __restrict__ z,          // (B, D)
    const float* __restrict__ mu,         // (C, K, D)
    const float* __restrict__ logits_pi,  // (C, K)
    const float* __restrict__ covL,       // (C, K, D, D)
    const float* __restrict__ prior,      // (C,)
    float* __restrict__ ws,               // (K, B, C) partial lp
    unsigned int* __restrict__ cnt,       // (C,) arrival counters, zeroed per call
    float* __restrict__ out)              // (B, C)
{
    __shared__ __align__(16) char E[27648];
    __shared__ float RD[DD];
    __shared__ float LOGV[DD];
    __shared__ unsigned int FLAG;

    const int bid = blockIdx.x;           // = c*2 + k
    const int c   = bid >> 1;
    const int k   = bid & 1;
    const int tid = threadIdx.x;
    const int w   = tid >> 6, l = tid & 63, l31 = l & 31, hp = l >> 5;
    const int off = l31 * 80 + 16 * hp;   // per-lane fragment offset in a block

    const float* Lm  = covL + (int64_t)(c*KK + k) * (DD*DD);
    const float* muv = mu + (size_t)(c*KK + k) * DD;

    // ---- phase A: diag gather (2 waves; 128 parallel strided loads)
    if (tid < DD) {
        float dg = Lm[(size_t)tid * DD + tid];
        RD[tid]   = 1.0f / dg;
        LOGV[tid] = __logf(dg);
    }
    __syncthreads();                      // B1: RD, LOGV ready

    // sld: every wave butterfly-reduces LOGV (all lanes get the sum)
    float sld = LOGV[l] + LOGV[64 + l];
    #pragma unroll
    for (int o = 1; o < 64; o <<= 1) sld += __shfl_xor(sld, o, 64);

    // ---- diag staging: re-load diag blocks (L2-hot), write Sm + Tt
    {
        const int r = (tid >> 3) & 31, c4 = tid & 7;
        const int n0 = 4*c4;
        #pragma unroll
        for (int ib = 0; ib < 4; ++ib) {
            float4 v = *(const float4*)(Lm + (size_t)(32*ib + r)*DD + 32*ib + 4*c4);
            float rdr = RD[32*ib + r];
            float se0 = (n0+0 < r) ? -v.x*rdr : 0.f;
            float se1 = (n0+1 < r) ? -v.y*rdr : 0.f;
            float se2 = (n0+2 < r) ? -v.z*rdr : 0.f;
            float se3 = (n0+3 < r) ? -v.w*rdr : 0.f;
            uint32_t tx = cvtpk((n0+0 == r) ? 1.f : se0, (n0+1 == r) ? 1.f : se1);
            uint32_t ty = cvtpk((n0+2 == r) ? 1.f : se2, (n0+3 == r) ? 1.f : se3);
            char* tt = E + 10240 + ib*2560 + 2*r;
            *(unsigned short*)(tt + (n0+0)*80) = (unsigned short)(tx & 0xffffu);
            *(unsigned short*)(tt + (n0+1)*80) = (unsigned short)(tx >> 16);
            *(unsigned short*)(tt + (n0+2)*80) = (unsigned short)(ty & 0xffffu);
            *(unsigned short*)(tt + (n0+3)*80) = (unsigned short)(ty >> 16);
            uint2 u; u.x = cvtpk(se0, se1); u.y = cvtpk(se2, se3);
            *(uint2*)(E + ib*2560 + r*80 + 8*c4) = u;
        }
    }
    __syncthreads();                      // B2: Sm, Tt ready

    // ---- M' compute: wave w owns tile w.  M' = (I + (-S)(I-S)) * D^-1
    {
        const char* SmB = E + w*2560;
        const char* TtB = E + 10240 + w*2560;
        bf16x8 A0 = *(const bf16x8*)(SmB + l31*80 + 16*hp);
        bf16x8 A1 = *(const bf16x8*)(SmB + l31*80 + 32 + 16*hp);
        bf16x8 B0 = *(const bf16x8*)(TtB + l31*80 + 16*hp);
        bf16x8 B1 = *(const bf16x8*)(TtB + l31*80 + 32 + 16*hp);
        f32x16 mm = zero16();
        mm = __builtin_amdgcn_mfma_f32_32x32x16_bf16(A0, B0, mm, 0,0,0);
        mm = __builtin_amdgcn_mfma_f32_32x32x16_bf16(A1, B1, mm, 0,0,0);
        float rdn = RD[32*w + l31];       // column scale (n = l31)
        char* SmW = E + w*2560;
        #pragma unroll
        for (int pe = 0; pe < 16; pe += 2) {
            int rowp = (pe&3) + 8*(pe>>2) + 4*hp;
            float m0 = (mm[pe]   + ((rowp     == l31) ? 1.f : 0.f)) * rdn;
            float m1 = (mm[pe+1] + ((rowp + 1 == l31) ? 1.f : 0.f)) * rdn;
            uint32_t mp = cvtpk(m0, m1);
            *(unsigned short*)(SmW + rowp*80     + 2*l31) = (unsigned short)(mp & 0xffffu);
            *(unsigned short*)(SmW + (rowp+1)*80 + 2*l31) = (unsigned short)(mp >> 16);
        }
    }
    __syncthreads();                      // B3: M' ready; Tt region now dead

    // ---- Eoff staging into [10240,25600) (overwrites dead Tt)
    #pragma unroll
    for (int rep = 0; rep < 6; ++rep) {   // 6 off-diag blocks * 32 rows * 8 float4
        int t2 = tid + 256*rep;
        int blk = t2 >> 8, r = (t2 >> 3) & 31, c4 = t2 & 7;
        // block list (i,j): (1,0)(2,0)(2,1)(3,0)(3,1)(3,2)
        int ib = 1 + (blk >= 1) + (blk >= 3);
        int jb = blk - ((ib * (ib - 1)) >> 1);
        float4 v = *(const float4*)(Lm + (size_t)(32*ib + r)*DD + 32*jb + 4*c4);
        uint2 u; u.x = cvtpk(-v.x, -v.y); u.y = cvtpk(-v.z, -v.w);
        *(uint2*)(E + 10240 + blk*2560 + r*80 + 8*c4) = u;
    }
    __syncthreads();                      // B4: Eoff ready

    // ---- solve BOTH batch halves sequentially (registers reused, not doubled)
    float lp_h0 = 0.f, lp_h1 = 0.f;       // my lp per half, kept for combine
    #pragma unroll 1
    for (int half = 0; half < 2; ++half) {
        const int bcol = half * 128 + w * 32 + l31;
        const float* zb = z + (size_t)bcol * DD;

        float macc = 0.f;
        f32x16 acc, yv;
        Frag8 tf, y0, y1, y2;

        #define LOAD_R(i)                                                        \
            do {                                                                 \
                _Pragma("unroll")                                                \
                for (int q = 0; q < 4; ++q) {                                    \
                    float4 zv = *(const float4*)(zb + 32*(i) + 8*q + 4*hp);      \
                    float4 mv = *(const float4*)(muv + 32*(i) + 8*q + 4*hp);     \
                    acc[4*q+0] = zv.x - mv.x;  acc[4*q+1] = zv.y - mv.y;         \
                    acc[4*q+2] = zv.z - mv.z;  acc[4*q+3] = zv.w - mv.w;         \
                }                                                                \
            } while (0)
        #define SQACC()                                                          \
            do {                                                                 \
                _Pragma("unroll")                                                \
                for (int p = 0; p < 16; ++p) macc += yv[p] * yv[p];              \
            } while (0)

        // i = 0
        LOAD_R(0);
        tf = build_frags(acc);
        yv = m_solve(E + 0*2560 + off, tf);
        SQACC();
        y0 = build_frags(yv);
        // i = 1   (off-diag block (1,0) = blk 0)
        LOAD_R(1);
        acc = off_apply(E + 10240 + 0*2560 + off, y0, acc);
        tf = build_frags(acc);
        yv = m_solve(E + 1*2560 + off, tf);
        SQACC();
        y1 = build_frags(yv);
        // i = 2   (blocks (2,0)=1, (2,1)=2)
        LOAD_R(2);
        acc = off_apply(E + 10240 + 1*2560 + off, y0, acc);
        acc = off_apply(E + 10240 + 2*2560 + off, y1, acc);
        tf = build_frags(acc);
        yv = m_solve(E + 2*2560 + off, tf);
        SQACC();
        y2 = build_frags(yv);
        // i = 3   (blocks (3,0)=3, (3,1)=4, (3,2)=5)
        LOAD_R(3);
        acc = off_apply(E + 10240 + 3*2560 + off, y0, acc);
        acc = off_apply(E + 10240 + 4*2560 + off, y1, acc);
        acc = off_apply(E + 10240 + 5*2560 + off, y2, acc);
        tf = build_frags(acc);
        yv = m_solve(E + 3*2560 + off, tf);
        SQACC();
        #undef LOAD_R
        #undef SQACC

        macc += __shfl_xor(macc, 32, 64); // combine row-halves per column

        const float CST = 235.2482645f;   // 128*log(2*pi)
        float lp = -0.5f * (macc + 2.f * sld + CST);
        if (half == 0) lp_h0 = lp; else lp_h1 = lp;
        if (hp == 0)
            ws[(size_t)k * (256 * CC) + (size_t)bcol * CC + c] = lp;
    }

    // ---- fold-in combine: second-arriving block of the c-pair does it.
    __threadfence();                      // release: my ws rows visible device-wide
    __syncthreads();                      // all threads' writes+fences complete
    if (tid == 0) FLAG = atomicAdd(cnt + c, 1u);
    __syncthreads();
    if (FLAG == 1u) {                     // partner finished first: its rows ready
        __threadfence();                  // acquire partner's ws rows
        if (hp == 0) {
            float pi0 = logits_pi[c*2+0], pi1 = logits_pi[c*2+1];
            float mp = fmaxf(pi0, pi1);
            float lsepi = mp + __logf(__expf(pi0-mp) + __expf(pi1-mp));
            float pr = prior[c];
            const size_t orow = (size_t)(1 - k) * (256 * CC);
            {   // half 0 column
                int bcol = w * 32 + l31;
                float other = ws[orow + (size_t)bcol * CC + c];
                float t0 = ((k == 0) ? lp_h0 : other) + pi0;   // lp(k=0)
                float t1 = ((k == 0) ? other : lp_h0) + pi1;   // lp(k=1)
                float mt = fmaxf(t0, t1);
                out[(size_t)bcol * CC + c] =
                    pr + mt + __logf(__expf(t0-mt) + __expf(t1-mt)) - lsepi;
            }
            {   // half 1 column
                int bcol = 128 + w * 32 + l31;
                float other = ws[orow + (size_t)bcol * CC + c];
                float t0 = ((k == 0) ? lp_h1 : other) + pi0;
                float t1 = ((k == 0) ? other : lp_h1) + pi1;
                float mt = fmaxf(t0, t1);
                out[(size_t)bcol * CC + c] =
                    pr + mt + __logf(__expf(t0-mt) + __expf(t1-mt)) - lsepi;
            }
        }
    }
}

extern "C" void kernel_launch(void* const* d_in, const int* in_sizes, int n_in,
                              void* d_out, int out_size, void* d_ws, size_t ws_size,
                              hipStream_t stream) {
    const float* z         = (const float*)d_in[0];
    const float* mu        = (const float*)d_in[1];
    const float* logits_pi = (const float*)d_in[2];
    const float* covL      = (const float*)d_in[3];
    const float* prior     = (const float*)d_in[4];
    float* out = (float*)d_out;
    float* wsLp = (float*)d_ws;                                  // 2.048 MB lp
    unsigned int* cnt = (unsigned int*)((char*)d_ws + 2048000);  // 4 KB counters

    hipMemsetAsync(cnt, 0, CC * sizeof(unsigned int), stream);   // per-call reset
    hipLaunchKernelGGL(mda_partial_kernel, dim3(2*CC), dim3(256), 0, stream,
                       z, mu, logits_pi, covL, prior, wsLp, cnt, out);
}

// Round 19
// 52.443 us; speedup vs baseline: 10.2166x; 10.2166x over previous
//
#include <hip/hip_runtime.h>
#include <cstdint>

#define CC 1000
#define KK 2
#define DD 128

typedef short bf16x8 __attribute__((ext_vector_type(8)));
typedef float f32x16 __attribute__((ext_vector_type(16)));
typedef int   i32x4  __attribute__((ext_vector_type(4)));
typedef unsigned int u32x2 __attribute__((ext_vector_type(2)));

// HW packed f32->bf16 (RTNE); 1 instr vs ~9 for the software pack.
__device__ __forceinline__ uint32_t cvtpk(float lo, float hi) {
    uint32_t r;
    asm("v_cvt_pk_bf16_f32 %0, %1, %2" : "=v"(r) : "v"(lo), "v"(hi));
    return r;
}
__device__ __forceinline__ f32x16 zero16() {
    f32x16 v;
    #pragma unroll
    for (int p = 0; p < 16; ++p) v[p] = 0.f;
    return v;
}

struct Frag8 { uint32_t a0, a1, a2, a3, b0, b1, b2, b3; };

__device__ __forceinline__ bf16x8 flo(const Frag8 f) {
    i32x4 t; t[0] = (int)f.a0; t[1] = (int)f.a1; t[2] = (int)f.a2; t[3] = (int)f.a3;
    return __builtin_bit_cast(bf16x8, t);
}
__device__ __forceinline__ bf16x8 fhi(const Frag8 f) {
    i32x4 t; t[0] = (int)f.b0; t[1] = (int)f.b1; t[2] = (int)f.b2; t[3] = (int)f.b3;
    return __builtin_bit_cast(bf16x8, t);
}

// C-layout fp32 tile -> B-fragment words (verified rounds 4..17).
// permlane32_swap(W2, W0): returns {out2=[W0.hi||W2.hi], out0=[W0.lo||W2.lo]}.
__device__ __forceinline__ Frag8 build_frags(const f32x16 t) {
    uint32_t W0 = cvtpk(t[0],  t[1]),  W1 = cvtpk(t[2],  t[3]);
    uint32_t W2 = cvtpk(t[4],  t[5]),  W3 = cvtpk(t[6],  t[7]);
    uint32_t W4 = cvtpk(t[8],  t[9]),  W5 = cvtpk(t[10], t[11]);
    uint32_t W6 = cvtpk(t[12], t[13]), W7 = cvtpk(t[14], t[15]);
    u32x2 p02 = __builtin_amdgcn_permlane32_swap(W2, W0, false, false);
    u32x2 p13 = __builtin_amdgcn_permlane32_swap(W3, W1, false, false);
    u32x2 p46 = __builtin_amdgcn_permlane32_swap(W6, W4, false, false);
    u32x2 p57 = __builtin_amdgcn_permlane32_swap(W7, W5, false, false);
    Frag8 f;
    f.a0 = p02[1]; f.a1 = p13[1]; f.a2 = p02[0]; f.a3 = p13[0];
    f.b0 = p46[1]; f.b1 = p57[1]; f.b2 = p46[0]; f.b3 = p57[0];
    return f;
}

__device__ __forceinline__ f32x16 off_apply(const char* Ep, const Frag8 yj, f32x16 acc) {
    bf16x8 A0 = *(const bf16x8*)(Ep);
    bf16x8 A1 = *(const bf16x8*)(Ep + 32);
    acc = __builtin_amdgcn_mfma_f32_32x32x16_bf16(A0, flo(yj), acc, 0, 0, 0);
    acc = __builtin_amdgcn_mfma_f32_32x32x16_bf16(A1, fhi(yj), acc, 0, 0, 0);
    return acc;
}
__device__ __forceinline__ f32x16 m_solve(const char* Mp, const Frag8 tf) {
    bf16x8 MA0 = *(const bf16x8*)(Mp);
    bf16x8 MA1 = *(const bf16x8*)(Mp + 32);
    f32x16 y = zero16();
    y = __builtin_amdgcn_mfma_f32_32x32x16_bf16(MA0, flo(tf), y, 0, 0, 0);
    y = __builtin_amdgcn_mfma_f32_32x32x16_bf16(MA1, fhi(tf), y, 0, 0, 0);
    return y;
}

// LDS layout (rows stride 80B):
//   [0,10240)      Sm:  4 diag blocks, first -S_i, overwritten by M'_i
//   [10240,20480)  Tt:  (I-S_i)^T (B-layout) -- DEAD after M' compute
//   [10240,25600)  Eoff: 6 off-diag -L_ij blocks, staged AFTER M' (overwrites Tt)
//   [25600,27648)  PAD: pins total LDS at 28672 B -> 5 blocks/CU implied ->
//                  RA budget 512/5 = 102 VGPR (round 17: verified win).
//
// ROUND-19 = ROUND-17 VERBATIM (best: 52.5us). Round-18's last-block-wins
// combine with __threadfence REVERTED: device-scope fences on 8-XCD gfx950
// compile to L2-writeback sequences; 2000 blocks x 2-3 fences serialized the
// cache-writeback engine -> 536us (10x). Cross-XCD coherence ops are
// catastrophically expensive -- keep the separate combine kernel.
__global__ __launch_bounds__(256, 1) void mda_partial_kernel(
    const float* __restrict__ z,          // (B, D)
    const float* __restrict__ mu,         // (C, K, D)
    const float* __restrict__ covL,       // (C, K, D, D)
    float* __restrict__ ws)               // (K, B, C) partial lp
{
    __shared__ __align__(16) char E[27648];
    __shared__ float RD[DD];
    __shared__ float LOGV[DD];

    const int bid = blockIdx.x;           // = c*2 + k
    const int c   = bid >> 1;
    const int k   = bid & 1;
    const int tid = threadIdx.x;
    const int w   = tid >> 6, l = tid & 63, l31 = l & 31, hp = l >> 5;
    const int off = l31 * 80 + 16 * hp;   // per-lane fragment offset in a block

    const float* Lm  = covL + (int64_t)(c*KK + k) * (DD*DD);
    const float* muv = mu + (size_t)(c*KK + k) * DD;

    // ---- phase A: diag gather (2 waves; 128 parallel strided loads)
    if (tid < DD) {
        float dg = Lm[(size_t)tid * DD + tid];
        RD[tid]   = 1.0f / dg;
        LOGV[tid] = __logf(dg);
    }
    __syncthreads();                      // B1: RD, LOGV ready

    // sld: every wave butterfly-reduces LOGV (all lanes get the sum)
    float sld = LOGV[l] + LOGV[64 + l];
    #pragma unroll
    for (int o = 1; o < 64; o <<= 1) sld += __shfl_xor(sld, o, 64);

    // ---- diag staging: re-load diag blocks (L2-hot), write Sm + Tt
    {
        const int r = (tid >> 3) & 31, c4 = tid & 7;
        const int n0 = 4*c4;
        #pragma unroll
        for (int ib = 0; ib < 4; ++ib) {
            float4 v = *(const float4*)(Lm + (size_t)(32*ib + r)*DD + 32*ib + 4*c4);
            float rdr = RD[32*ib + r];
            float se0 = (n0+0 < r) ? -v.x*rdr : 0.f;
            float se1 = (n0+1 < r) ? -v.y*rdr : 0.f;
            float se2 = (n0+2 < r) ? -v.z*rdr : 0.f;
            float se3 = (n0+3 < r) ? -v.w*rdr : 0.f;
            uint32_t tx = cvtpk((n0+0 == r) ? 1.f : se0, (n0+1 == r) ? 1.f : se1);
            uint32_t ty = cvtpk((n0+2 == r) ? 1.f : se2, (n0+3 == r) ? 1.f : se3);
            char* tt = E + 10240 + ib*2560 + 2*r;
            *(unsigned short*)(tt + (n0+0)*80) = (unsigned short)(tx & 0xffffu);
            *(unsigned short*)(tt + (n0+1)*80) = (unsigned short)(tx >> 16);
            *(unsigned short*)(tt + (n0+2)*80) = (unsigned short)(ty & 0xffffu);
            *(unsigned short*)(tt + (n0+3)*80) = (unsigned short)(ty >> 16);
            uint2 u; u.x = cvtpk(se0, se1); u.y = cvtpk(se2, se3);
            *(uint2*)(E + ib*2560 + r*80 + 8*c4) = u;
        }
    }
    __syncthreads();                      // B2: Sm, Tt ready

    // ---- M' compute: wave w owns tile w.  M' = (I + (-S)(I-S)) * D^-1
    {
        const char* SmB = E + w*2560;
        const char* TtB = E + 10240 + w*2560;
        bf16x8 A0 = *(const bf16x8*)(SmB + l31*80 + 16*hp);
        bf16x8 A1 = *(const bf16x8*)(SmB + l31*80 + 32 + 16*hp);
        bf16x8 B0 = *(const bf16x8*)(TtB + l31*80 + 16*hp);
        bf16x8 B1 = *(const bf16x8*)(TtB + l31*80 + 32 + 16*hp);
        f32x16 mm = zero16();
        mm = __builtin_amdgcn_mfma_f32_32x32x16_bf16(A0, B0, mm, 0,0,0);
        mm = __builtin_amdgcn_mfma_f32_32x32x16_bf16(A1, B1, mm, 0,0,0);
        float rdn = RD[32*w + l31];       // column scale (n = l31)
        char* SmW = E + w*2560;
        #pragma unroll
        for (int pe = 0; pe < 16; pe += 2) {
            int rowp = (pe&3) + 8*(pe>>2) + 4*hp;
            float m0 = (mm[pe]   + ((rowp     == l31) ? 1.f : 0.f)) * rdn;
            float m1 = (mm[pe+1] + ((rowp + 1 == l31) ? 1.f : 0.f)) * rdn;
            uint32_t mp = cvtpk(m0, m1);
            *(unsigned short*)(SmW + rowp*80     + 2*l31) = (unsigned short)(mp & 0xffffu);
            *(unsigned short*)(SmW + (rowp+1)*80 + 2*l31) = (unsigned short)(mp >> 16);
        }
    }
    __syncthreads();                      // B3: M' ready; Tt region now dead

    // ---- Eoff staging into [10240,25600) (overwrites dead Tt)
    #pragma unroll
    for (int rep = 0; rep < 6; ++rep) {   // 6 off-diag blocks * 32 rows * 8 float4
        int t2 = tid + 256*rep;
        int blk = t2 >> 8, r = (t2 >> 3) & 31, c4 = t2 & 7;
        // block list (i,j): (1,0)(2,0)(2,1)(3,0)(3,1)(3,2)
        int ib = 1 + (blk >= 1) + (blk >= 3);
        int jb = blk - ((ib * (ib - 1)) >> 1);
        float4 v = *(const float4*)(Lm + (size_t)(32*ib + r)*DD + 32*jb + 4*c4);
        uint2 u; u.x = cvtpk(-v.x, -v.y); u.y = cvtpk(-v.z, -v.w);
        *(uint2*)(E + 10240 + blk*2560 + r*80 + 8*c4) = u;
    }
    __syncthreads();                      // B4: Eoff ready

    // ---- solve BOTH batch halves sequentially (registers reused, not doubled)
    #pragma unroll 1
    for (int half = 0; half < 2; ++half) {
        const int bcol = half * 128 + w * 32 + l31;
        const float* zb = z + (size_t)bcol * DD;

        float macc = 0.f;
        f32x16 acc, yv;
        Frag8 tf, y0, y1, y2;

        #define LOAD_R(i)                                                        \
            do {                                                                 \
                _Pragma("unroll")                                                \
                for (int q = 0; q < 4; ++q) {                                    \
                    float4 zv = *(const float4*)(zb + 32*(i) + 8*q + 4*hp);      \
                    float4 mv = *(const float4*)(muv + 32*(i) + 8*q + 4*hp);     \
                    acc[4*q+0] = zv.x - mv.x;  acc[4*q+1] = zv.y - mv.y;         \
                    acc[4*q+2] = zv.z - mv.z;  acc[4*q+3] = zv.w - mv.w;         \
                }                                                                \
            } while (0)
        #define SQACC()                                                          \
            do {                                                                 \
                _Pragma("unroll")                                                \
                for (int p = 0; p < 16; ++p) macc += yv[p] * yv[p];              \
            } while (0)

        // i = 0
        LOAD_R(0);
        tf = build_frags(acc);
        yv = m_solve(E + 0*2560 + off, tf);
        SQACC();
        y0 = build_frags(yv);
        // i = 1   (off-diag block (1,0) = blk 0)
        LOAD_R(1);
        acc = off_apply(E + 10240 + 0*2560 + off, y0, acc);
        tf = build_frags(acc);
        yv = m_solve(E + 1*2560 + off, tf);
        SQACC();
        y1 = build_frags(yv);
        // i = 2   (blocks (2,0)=1, (2,1)=2)
        LOAD_R(2);
        acc = off_apply(E + 10240 + 1*2560 + off, y0, acc);
        acc = off_apply(E + 10240 + 2*2560 + off, y1, acc);
        tf = build_frags(acc);
        yv = m_solve(E + 2*2560 + off, tf);
        SQACC();
        y2 = build_frags(yv);
        // i = 3   (blocks (3,0)=3, (3,1)=4, (3,2)=5)
        LOAD_R(3);
        acc = off_apply(E + 10240 + 3*2560 + off, y0, acc);
        acc = off_apply(E + 10240 + 4*2560 + off, y1, acc);
        acc = off_apply(E + 10240 + 5*2560 + off, y2, acc);
        tf = build_frags(acc);
        yv = m_solve(E + 3*2560 + off, tf);
        SQACC();
        #undef LOAD_R
        #undef SQACC

        macc += __shfl_xor(macc, 32, 64); // combine row-halves per column

        const float CST = 235.2482645f;   // 128*log(2*pi)
        float lp = -0.5f * (macc + 2.f * sld + CST);
        if (hp == 0)
            ws[(size_t)k * (256 * CC) + (size_t)bcol * CC + c] = lp;
    }
}

// out[b,c] = prior[c] + LSE_k(lp_k + pi_k) - LSE_k(pi_k). Fully coalesced.
__global__ __launch_bounds__(256) void mda_combine_kernel(
    const float* __restrict__ lp,         // (K, B, C)
    const float* __restrict__ logits_pi,  // (C, K)
    const float* __restrict__ prior,      // (C,)
    float* __restrict__ out)              // (B, C)
{
    int idx = blockIdx.x * 256 + threadIdx.x;    // = b*CC + c
    int c = idx % CC;
    float lp0 = lp[idx];
    float lp1 = lp[256 * CC + idx];
    float pi0 = logits_pi[c*2+0], pi1 = logits_pi[c*2+1];
    float mp = fmaxf(pi0, pi1);
    float lsepi = mp + __logf(__expf(pi0-mp) + __expf(pi1-mp));
    float t0 = lp0 + pi0, t1 = lp1 + pi1;
    float mt = fmaxf(t0, t1);
    out[idx] = prior[c] + mt + __logf(__expf(t0-mt) + __expf(t1-mt)) - lsepi;
}

extern "C" void kernel_launch(void* const* d_in, const int* in_sizes, int n_in,
                              void* d_out, int out_size, void* d_ws, size_t ws_size,
                              hipStream_t stream) {
    const float* z         = (const float*)d_in[0];
    const float* mu        = (const float*)d_in[1];
    const float* logits_pi = (const float*)d_in[2];
    const float* covL      = (const float*)d_in[3];
    const float* prior     = (const float*)d_in[4];
    float* out = (float*)d_out;
    float* wsLp = (float*)d_ws;   // 2.048 MB

    hipLaunchKernelGGL(mda_partial_kernel, dim3(2*CC), dim3(256), 0, stream,
                       z, mu, covL, wsLp);
    hipLaunchKernelGGL(mda_combine_kernel, dim3(256 * CC / 256), dim3(256), 0, stream,
                       wsLp, logits_pi, prior, out);
}